// Round 1
// baseline (319.212 us; speedup 1.0000x reference)
//
#include <hip/hip_runtime.h>

// perm_inv_n: x[256,512,64] fp32 ->
//   per z (flat, concatenated): cs[64] | gram[64x64] | ss[64] | cs^2[64] | (gram x cs)[64^3]
#define Z_DIM 256
#define A_DIM 512
#define B_DIM 64
#define PER_Z 266432
#define GRAM_OFF 64
#define H3_OFF 4160
#define H4_OFF 4224
#define H5_OFF 4288
#define CHUNK 128

// One block per z. 256 threads = 16x16 grid of 4x4 register tiles covering the
// 64x64 gram. LDS stages 128 rows of x[z] at a time (32 KB).
__global__ __launch_bounds__(256) void k_stats(const float* __restrict__ x,
                                               float* __restrict__ out) {
    __shared__ float sx[CHUNK * B_DIM];  // 32 KB
    const int z = blockIdx.x;
    const int t = threadIdx.x;
    const float* xz = x + (size_t)z * (A_DIM * B_DIM);
    float* oz = out + (size_t)z * PER_Z;

    const int tb = t >> 4;   // 0..15 -> rows tb*4..tb*4+3
    const int tc = t & 15;   // 0..15 -> cols tc*4..tc*4+3

    float acc[4][4];
#pragma unroll
    for (int i = 0; i < 4; i++)
#pragma unroll
        for (int j = 0; j < 4; j++) acc[i][j] = 0.f;

    float cs_acc = 0.f, ss_acc = 0.f;  // used by threads < 64 only

    for (int a0 = 0; a0 < A_DIM; a0 += CHUNK) {
        // stage CHUNK x 64 floats: 2048 float4, 8 per thread, coalesced
        const float4* src = (const float4*)(xz + a0 * B_DIM);
        float4* dst = (float4*)sx;
#pragma unroll
        for (int i = 0; i < 8; i++) dst[t + i * 256] = src[t + i * 256];
        __syncthreads();

        for (int a = 0; a < CHUNK; a++) {
            float4 bv = *(const float4*)&sx[a * B_DIM + tb * 4];
            float4 cv = *(const float4*)&sx[a * B_DIM + tc * 4];
            float bb[4] = {bv.x, bv.y, bv.z, bv.w};
            float cc[4] = {cv.x, cv.y, cv.z, cv.w};
#pragma unroll
            for (int i = 0; i < 4; i++)
#pragma unroll
                for (int j = 0; j < 4; j++)
                    acc[i][j] = fmaf(bb[i], cc[j], acc[i][j]);
        }

        if (t < B_DIM) {  // wave 0 only: column sum + sum of squares
#pragma unroll 4
            for (int a = 0; a < CHUNK; a++) {
                float v = sx[a * B_DIM + t];
                cs_acc += v;
                ss_acc = fmaf(v, v, ss_acc);
            }
        }
        __syncthreads();  // protect sx before next chunk overwrite
    }

    // gram tile -> out (coalesced float4 rows)
#pragma unroll
    for (int i = 0; i < 4; i++) {
        float4 v = make_float4(acc[i][0], acc[i][1], acc[i][2], acc[i][3]);
        *(float4*)&oz[GRAM_OFF + (size_t)(tb * 4 + i) * B_DIM + tc * 4] = v;
    }
    if (t < B_DIM) {
        oz[t] = cs_acc;                   // h1
        oz[H3_OFF + t] = ss_acc;          // h3
        oz[H4_OFF + t] = cs_acc * cs_acc; // h4
    }
}

// h5[z][b][c][d] = gram[z][bc] * cs[z][d]. 64 blocks per z; each thread stores
// 4 float4 (store-bound; gram/cs reads are L1-broadcast).
__global__ __launch_bounds__(256) void k_outer(float* __restrict__ out) {
    const int z = blockIdx.x >> 6;
    const int s = blockIdx.x & 63;
    const int t = threadIdx.x;
    float* oz = out + (size_t)z * PER_Z;
    const float* gram = oz + GRAM_OFF;
    const float* cs = oz;
    float4* o5 = (float4*)(oz + H5_OFF);
#pragma unroll
    for (int i = 0; i < 4; i++) {
        int q = s * 1024 + i * 256 + t;  // float4 index in [0, 65536)
        int bc = q >> 4;                 // which gram element
        int dg = q & 15;                 // which float4 of cs
        float g = gram[bc];
        float4 c4 = *(const float4*)&cs[dg * 4];
        o5[q] = make_float4(g * c4.x, g * c4.y, g * c4.z, g * c4.w);
    }
}

extern "C" void kernel_launch(void* const* d_in, const int* in_sizes, int n_in,
                              void* d_out, int out_size, void* d_ws, size_t ws_size,
                              hipStream_t stream) {
    const float* x = (const float*)d_in[0];
    float* out = (float*)d_out;
    k_stats<<<Z_DIM, 256, 0, stream>>>(x, out);
    k_outer<<<Z_DIM * 64, 256, 0, stream>>>(out);
}

// Round 3
// 308.830 us; speedup vs baseline: 1.0336x; 1.0336x over previous
//
#include <hip/hip_runtime.h>

// perm_inv_n: x[256,512,64] fp32 ->
//   per z (flat): cs[64] | gram[64x64] | ss[64] | cs^2[64] | (gram x cs)[64^3]
// Single fused kernel: 1 block per z, 512 threads (8 waves/CU).
#define Z_DIM 256
#define A_DIM 512
#define B_DIM 64
#define PER_Z 266432
#define GRAM_OFF 64
#define H3_OFF 4160
#define H4_OFF 4224
#define H5_OFF 4288
#define CHUNK 128

typedef float f4v __attribute__((ext_vector_type(4)));  // native vec for nontemporal

__global__ __launch_bounds__(512) void k_fused(const float* __restrict__ x,
                                               float* __restrict__ out) {
    __shared__ float sx[2][CHUNK * B_DIM];  // 64 KB staging (one chunk per half)
    __shared__ float sg[B_DIM * B_DIM];     // 16 KB final gram
    __shared__ float scs1[B_DIM];           // half-1 partial col sums
    __shared__ float scs[B_DIM];            // final col sums

    const int z = blockIdx.x;
    const int t = threadIdx.x;
    const int half = t >> 8;   // 0 or 1
    const int u = t & 255;
    const int tb = u >> 4;     // 0..15 -> gram rows tb*4..tb*4+3
    const int tc = u & 15;     // 0..15 -> gram cols tc*4..tc*4+3

    const float* xz = x + (size_t)z * (A_DIM * B_DIM);
    float* oz = out + (size_t)z * PER_Z;

    float acc[4][4];
#pragma unroll
    for (int i = 0; i < 4; i++)
#pragma unroll
        for (int j = 0; j < 4; j++) acc[i][j] = 0.f;
    float cs_acc = 0.f;

    float* my_sx = sx[half];

    // Each half processes 2 chunks of 128 rows: half h takes chunks {h, h+2}.
    for (int c = 0; c < 2; c++) {
        const int a0 = (c * 2 + half) * CHUNK;
        // stage CHUNK x 64 floats per half: 2048 float4, 8 per thread, coalesced
        const float4* src = (const float4*)(xz + a0 * B_DIM);
        float4* dst = (float4*)my_sx;
#pragma unroll
        for (int i = 0; i < 8; i++) dst[u + i * 256] = src[u + i * 256];
        __syncthreads();

        for (int a = 0; a < CHUNK; a++) {
            float4 bv = *(const float4*)&my_sx[a * B_DIM + tb * 4];
            float4 cv = *(const float4*)&my_sx[a * B_DIM + tc * 4];
            float bb[4] = {bv.x, bv.y, bv.z, bv.w};
            float cc[4] = {cv.x, cv.y, cv.z, cv.w};
#pragma unroll
            for (int i = 0; i < 4; i++)
#pragma unroll
                for (int j = 0; j < 4; j++)
                    acc[i][j] = fmaf(bb[i], cc[j], acc[i][j]);
        }
        if (u < B_DIM) {  // first wave of each half: partial column sums
#pragma unroll 4
            for (int a = 0; a < CHUNK; a++) cs_acc += my_sx[a * B_DIM + u];
        }
        __syncthreads();
    }

    // --- reduce the two halves ---
    if (half) {
#pragma unroll
        for (int i = 0; i < 4; i++) {
            float4 v = make_float4(acc[i][0], acc[i][1], acc[i][2], acc[i][3]);
            *(float4*)&sg[(tb * 4 + i) * B_DIM + tc * 4] = v;
        }
        if (u < B_DIM) scs1[u] = cs_acc;
    }
    __syncthreads();
    if (!half) {
#pragma unroll
        for (int i = 0; i < 4; i++) {
            float4 p = *(const float4*)&sg[(tb * 4 + i) * B_DIM + tc * 4];
            float4 v = make_float4(acc[i][0] + p.x, acc[i][1] + p.y,
                                   acc[i][2] + p.z, acc[i][3] + p.w);
            *(float4*)&sg[(tb * 4 + i) * B_DIM + tc * 4] = v;       // final gram (LDS)
            *(float4*)&oz[GRAM_OFF + (size_t)(tb * 4 + i) * B_DIM + tc * 4] = v;  // h2
        }
        if (u < B_DIM) {
            float c = cs_acc + scs1[u];
            scs[u] = c;
            oz[u] = c;                 // h1
            oz[H4_OFF + u] = c * c;    // h4
        }
    }
    __syncthreads();
    if (!half && u < B_DIM) oz[H3_OFF + u] = sg[u * B_DIM + u];  // h3 = gram diagonal

    // --- phase 3: h5[b][c][d] = gram[b*64+c] * cs[d], 65536 float4, 128/thread ---
    f4v* o5 = (f4v*)(oz + H5_OFF);
#pragma unroll 4
    for (int i = 0; i < 128; i++) {
        int q = i * 512 + t;
        int bc = q >> 4;
        int dg = q & 15;
        float g = sg[bc];
        const float* c4 = &scs[dg * 4];
        f4v v = {g * c4[0], g * c4[1], g * c4[2], g * c4[3]};
        __builtin_nontemporal_store(v, &o5[q]);
    }
}

extern "C" void kernel_launch(void* const* d_in, const int* in_sizes, int n_in,
                              void* d_out, int out_size, void* d_ws, size_t ws_size,
                              hipStream_t stream) {
    const float* x = (const float*)d_in[0];
    float* out = (float*)d_out;
    k_fused<<<Z_DIM, 512, 0, stream>>>(x, out);
}